// Round 7
// baseline (26.853 us; speedup 1.0000x reference)
//
#include <hip/hip_runtime.h>

// Son_swapnet: out[b,i] = sum_j d*leaky01(t3)*(-w3[e(i,j)]),
//   d  = x[b,i]*w1[i] - x[b,j]*w1[j]
//   s = d*d; t3 = (c0 + c2*s) + |d|*(c1 + c3*s)   [even/odd split, shallow chain]
//   leaky01(t) = max(t, 0.01t)
// j==i contributes exactly 0 (W[i][i] = 0).
//
// build_W materializes W[i][j] = -w3[e(i,j)] (256 KB in d_ws).
// son_kernel: wave = node i; W row enters via SCALAR loads in 64-value chunks
// (4x s_load_dwordx16 + one lgkmcnt(0) per 16-jc chunk) -> zero LDS reads for W,
// inner loop = 1 swizzled ds_read_b128 + pure VALU. Waves phase-offset by (w&3)
// chunks to break the post-barrier LDS convoy.

#define C_NODES 256
#define BT      64      // batches per block (one per lane)
#define NW      8       // waves per block (512 threads), 1 node per wave

typedef float f32x16 __attribute__((ext_vector_type(16)));

__global__ __launch_bounds__(256) void build_W(const float* __restrict__ w3,
                                               float* __restrict__ W)
{
    const int i = blockIdx.x;
    const int j = threadIdx.x;
    const int p = (i < j) ? i : j;
    const int q = (i < j) ? j : i;
    W[(i << 8) + j] = (i == j) ? 0.f
                    : -w3[(p * (511 - p)) / 2 + q - p - 1];
}

__global__ __launch_bounds__(512, 4) void son_kernel(
    const float* __restrict__ x, const float* __restrict__ w1,
    const float* __restrict__ w2, const float* __restrict__ W,
    float* __restrict__ out)
{
    // o1t: [row=batch][channel], 256 words/row, 16B-chunk XOR-swizzled by (row&7)
    __shared__ __align__(16) float o1t[BT * C_NODES];       // 64 KiB

    const int t  = threadIdx.x;
    const int b0 = blockIdx.x * BT;

    // ---- stage o1t (coalesced global float4 reads; swizzled LDS writes)
    {
        const int chunk = t & 63;            // 16B chunk within row
        const int c4    = chunk << 2;        // channel
        const float4 w1v = *(const float4*)&w1[c4];
        #pragma unroll
        for (int p = 0; p < 8; ++p) {
            const int row = (t >> 6) + (p << 3);          // 0..63
            const float4 xv = *(const float4*)&x[(b0 + row) * C_NODES + c4];
            float4 o;
            o.x = xv.x * w1v.x; o.y = xv.y * w1v.y;
            o.z = xv.z * w1v.z; o.w = xv.w * w1v.w;
            const int phys = chunk ^ (row & 7);
            *(float4*)&o1t[(row << 8) + (phys << 2)] = o;
        }
    }
    __syncthreads();

    const int lane    = t & 63;
    const int w       = __builtin_amdgcn_readfirstlane(t >> 6);
    const int i       = blockIdx.y * NW + w;
    const int swz     = lane & 7;
    const int rowbase = lane << 8;

    const float c0 = w2[0], c1 = w2[1], c2 = w2[2], c3 = w2[3];
    const float* __restrict__ Wrow = W + (i << 8);   // uniform

    // own-node o1 value (swizzled one-time read)
    const float oi = o1t[rowbase + ((((i >> 2) ^ swz) << 2) | (i & 3))];

    float acc0 = 0.f, acc1 = 0.f, acc2 = 0.f, acc3 = 0.f;

    #pragma unroll 1
    for (int cc = 0; cc < 4; ++cc) {
        const int ch = (cc + w) & 3;          // phase-desync across waves
        const float* wp = Wrow + (ch << 6);   // 64 W values for this chunk
        f32x16 wA, wB, wC, wD;
        asm volatile(
            "s_load_dwordx16 %0, %4, 0x0\n\t"
            "s_load_dwordx16 %1, %4, 0x40\n\t"
            "s_load_dwordx16 %2, %4, 0x80\n\t"
            "s_load_dwordx16 %3, %4, 0xc0\n\t"
            "s_waitcnt lgkmcnt(0)"
            : "=s"(wA), "=s"(wB), "=s"(wC), "=s"(wD)
            : "s"(wp)
            : "memory");
        const int jbase = ch << 4;
        #pragma unroll
        for (int k = 0; k < 16; ++k) {
            const float4 ov = *(const float4*)&o1t[rowbase + (((jbase + k) ^ swz) << 2)];
            #pragma unroll
            for (int e = 0; e < 4; ++e) {
                const float oj  = ((const float*)&ov)[e];
                const float wv  = (k < 4 ? wA : k < 8 ? wB : k < 12 ? wC : wD)
                                  [(k & 3) * 4 + e];          // SGPR, const index
                const float d   = oi - oj;
                const float s   = d * d;
                const float pe  = __builtin_fmaf(s, c2, c0);  // even part
                const float po  = __builtin_fmaf(s, c3, c1);  // odd part
                const float t3  = __builtin_fmaf(fabsf(d), po, pe); // |d| = modifier
                const float t3s = fmaxf(t3, 0.01f * t3);
                const float u   = d * t3s;
                if (e == 0) acc0 = __builtin_fmaf(u, wv, acc0);
                else if (e == 1) acc1 = __builtin_fmaf(u, wv, acc1);
                else if (e == 2) acc2 = __builtin_fmaf(u, wv, acc2);
                else acc3 = __builtin_fmaf(u, wv, acc3);
            }
        }
    }

    out[(b0 + lane) * C_NODES + i] = (acc0 + acc1) + (acc2 + acc3);
}

extern "C" void kernel_launch(void* const* d_in, const int* in_sizes, int n_in,
                              void* d_out, int out_size, void* d_ws, size_t ws_size,
                              hipStream_t stream) {
    const float* x  = (const float*)d_in[0];
    const float* w1 = (const float*)d_in[1];
    const float* w2 = (const float*)d_in[2];
    const float* w3 = (const float*)d_in[3];
    float* out = (float*)d_out;
    float* W   = (float*)d_ws;                    // 256*256*4 = 256 KB scratch

    build_W<<<C_NODES, C_NODES, 0, stream>>>(w3, W);

    const int B = in_sizes[0] / C_NODES;          // 1024
    dim3 grid(B / BT, C_NODES / NW);              // 16 x 32 = 512 blocks = 2/CU
    son_kernel<<<grid, 512, 0, stream>>>(x, w1, w2, W, out);
}

// Round 8
// 25.050 us; speedup vs baseline: 1.0720x; 1.0720x over previous
//
#include <hip/hip_runtime.h>

// Son_swapnet: out[b,i] = sum_j d*leaky01(t3)*(-w3[e(i,j)]),
//   d  = x[b,i]*w1[i] - x[b,j]*w1[j]
//   t3 = c0 + a*(c1 + a*(c2 + a*c3)), a = |d| (folds to fma abs-modifier)
//   leaky01(t) = max(t, 0.01t)
// j==i contributes exactly 0 (W[i][i] = 0).
//
// build_W materializes W[i][j] = -w3[e(i,j)] (256 KB in d_ws).
// son_kernel: wave = node i; lane = (j-half, batch row 0..31). Half-wave split:
// lanes 0-31 cover j in [0,128), lanes 32-63 j in [128,256); __shfl_xor merge.
// LDS 40KB + __launch_bounds__(512,6) -> 3 blocks/CU = 24 waves/CU (6/SIMD),
// vs R4's 16 waves/CU: goal is LDS<->VALU overlap across waves.

#define C_NODES 256
#define BT      32      // batches per block
#define NW      8       // waves per block (512 threads), 1 node per wave

__global__ __launch_bounds__(256) void build_W(const float* __restrict__ w3,
                                               float* __restrict__ W)
{
    const int i = blockIdx.x;
    const int j = threadIdx.x;
    const int p = (i < j) ? i : j;
    const int q = (i < j) ? j : i;
    W[(i << 8) + j] = (i == j) ? 0.f
                    : -w3[(p * (511 - p)) / 2 + q - p - 1];
}

__global__ __launch_bounds__(512, 6) void son_kernel(
    const float* __restrict__ x, const float* __restrict__ w1,
    const float* __restrict__ w2, const float* __restrict__ W,
    float* __restrict__ out)
{
    // o1t: [row=batch 0..31][channel], 256 words/row, 16B-chunk XOR-swizzled (row&7)
    __shared__ __align__(16) float o1t[BT * C_NODES];       // 32 KiB
    __shared__ __align__(16) float wrow[NW * C_NODES];      // 8 KiB

    const int t  = threadIdx.x;
    const int b0 = blockIdx.x * BT;

    // ---- stage o1t (coalesced global float4 reads; swizzled LDS writes)
    {
        const int chunk = t & 63;            // 16B chunk within row
        const int c4    = chunk << 2;        // channel
        const float4 w1v = *(const float4*)&w1[c4];
        #pragma unroll
        for (int p = 0; p < 4; ++p) {
            const int row = (t >> 6) + (p << 3);          // 0..31
            const float4 xv = *(const float4*)&x[(b0 + row) * C_NODES + c4];
            float4 o;
            o.x = xv.x * w1v.x; o.y = xv.y * w1v.y;
            o.z = xv.z * w1v.z; o.w = xv.w * w1v.w;
            const int phys = chunk ^ (row & 7);
            *(float4*)&o1t[(row << 8) + (phys << 2)] = o;
        }
    }

    // ---- gather wrow[w][j] = -w3[e(i,j)] == W[i][j]  (L2-resident, once)
    {
        const int lane = t & 63;
        const int wv_  = t >> 6;             // wave = node slot
        const int i    = blockIdx.y * NW + wv_;
        *(float4*)&wrow[(wv_ << 8) + (lane << 2)] =
            *(const float4*)&W[(i << 8) + (lane << 2)];
    }
    __syncthreads();

    const int lane    = t & 63;
    const int w       = __builtin_amdgcn_readfirstlane(t >> 6);
    const int i       = blockIdx.y * NW + w;
    const int row     = lane & 31;                 // batch within tile
    const int hbit    = lane & 32;                 // j-half selector (bit 5)
    const int swz     = row & 7;
    const int rowbase = row << 8;

    const float c0 = w2[0], c1 = w2[1], c2 = w2[2], c3 = w2[3];

    // own-node o1 value (swizzled one-time read, exact f32)
    const float oi = o1t[rowbase + ((((i >> 2) ^ swz) << 2) | (i & 3))];

    float acc0 = 0.f, acc1 = 0.f, acc2 = 0.f, acc3 = 0.f;

    #pragma unroll 4
    for (int jc = 0; jc < 32; ++jc) {
        const int cj = hbit + jc;                              // chunk 0..63
        const float4 ov = *(const float4*)&o1t[rowbase + ((cj ^ swz) << 2)];
        const float4 wa = *(const float4*)&wrow[(w << 8) + (cj << 2)]; // 2-addr bcast

        {   const float d = oi - ov.x, a = fabsf(d);
            const float t3 = __builtin_fmaf(a, __builtin_fmaf(a,
                               __builtin_fmaf(a, c3, c2), c1), c0);
            acc0 = __builtin_fmaf(d * fmaxf(t3, 0.01f * t3), wa.x, acc0); }
        {   const float d = oi - ov.y, a = fabsf(d);
            const float t3 = __builtin_fmaf(a, __builtin_fmaf(a,
                               __builtin_fmaf(a, c3, c2), c1), c0);
            acc1 = __builtin_fmaf(d * fmaxf(t3, 0.01f * t3), wa.y, acc1); }
        {   const float d = oi - ov.z, a = fabsf(d);
            const float t3 = __builtin_fmaf(a, __builtin_fmaf(a,
                               __builtin_fmaf(a, c3, c2), c1), c0);
            acc2 = __builtin_fmaf(d * fmaxf(t3, 0.01f * t3), wa.z, acc2); }
        {   const float d = oi - ov.w, a = fabsf(d);
            const float t3 = __builtin_fmaf(a, __builtin_fmaf(a,
                               __builtin_fmaf(a, c3, c2), c1), c0);
            acc3 = __builtin_fmaf(d * fmaxf(t3, 0.01f * t3), wa.w, acc3); }
    }

    float acc = (acc0 + acc1) + (acc2 + acc3);
    acc += __shfl_xor(acc, 32, 64);                // merge j-halves
    if (lane < 32)
        out[(b0 + row) * C_NODES + i] = acc;
}

extern "C" void kernel_launch(void* const* d_in, const int* in_sizes, int n_in,
                              void* d_out, int out_size, void* d_ws, size_t ws_size,
                              hipStream_t stream) {
    const float* x  = (const float*)d_in[0];
    const float* w1 = (const float*)d_in[1];
    const float* w2 = (const float*)d_in[2];
    const float* w3 = (const float*)d_in[3];
    float* out = (float*)d_out;
    float* W   = (float*)d_ws;                    // 256*256*4 = 256 KB scratch

    build_W<<<C_NODES, C_NODES, 0, stream>>>(w3, W);

    const int B = in_sizes[0] / C_NODES;          // 1024
    dim3 grid(B / BT, C_NODES / NW);              // 32 x 32 = 1024 blocks
    son_kernel<<<grid, 512, 0, stream>>>(x, w1, w2, W, out);
}

// Round 9
// 23.820 us; speedup vs baseline: 1.1273x; 1.0516x over previous
//
#include <hip/hip_runtime.h>

// Son_swapnet: out[b,i] = sum_j d*leaky01(t3)*(-w3[e(i,j)]),
//   d  = o1[b][i] - o1[b][j],  o1 = x*w1
//   t3 = c0 + a*(c1 + a*(c2 + a*c3)), a = |d|;  leaky01(t) = max(t, 0.01t)
// j==i contributes exactly 0 (wv entry forced to 0).
//
// Layout (lane = j-group): 512 thr = 8 waves; wave w owns nodes i0=2w+16*by, i0+1.
// Lane l owns partners j in {4l..4l+3}; W values live in VGPRs (global gather, once).
// Per batch b: ONE linear ds_read_b128 (full row, bank-balanced) + ONE uniform
// b64 broadcast (oi pair). acc[b].{x,y} per lane; cross-lane sum via per-wave
// LDS transpose (pad-68 rows) + shfl_xor(16/32) epilogue after a barrier.

#define C_NODES 256
#define BT      32     // batches per block
#define NW      8      // waves per block (512 threads)
#define NPB     16     // nodes per block (2 per wave)

__global__ __launch_bounds__(512, 4) void son_kernel(
    const float* __restrict__ x, const float* __restrict__ w1,
    const float* __restrict__ w2, const float* __restrict__ w3,
    float* __restrict__ out)
{
    // 32 rows x 256 ch (32KB) for o1; reused after barrier as 8 x [16][68] red
    __shared__ __align__(16) float o1t[8704];

    const int t    = threadIdx.x;
    const int lane = t & 63;
    const int w    = t >> 6;                      // 0..7
    const int b0   = blockIdx.x * BT;
    const int i0   = blockIdx.y * NPB + 2 * w;    // even

    // ---- per-lane W gather (global, L2-resident; overlaps staging latency)
    float4 wv0, wv1;
    #pragma unroll
    for (int k = 0; k < 4; ++k) {
        const int j = 4 * lane + k;
        {   const int p = (i0 < j) ? i0 : j, q = (i0 < j) ? j : i0;
            ((float*)&wv0)[k] = (i0 == j) ? 0.f
                               : -w3[(p * (511 - p)) / 2 + q - p - 1]; }
        {   const int i1 = i0 + 1;
            const int p = (i1 < j) ? i1 : j, q = (i1 < j) ? j : i1;
            ((float*)&wv1)[k] = (i1 == j) ? 0.f
                               : -w3[(p * (511 - p)) / 2 + q - p - 1]; }
    }

    // ---- stage o1t[b][ch] = x[b0+b][ch] * w1[ch]  (linear, conflict-free)
    {
        const int c4 = lane << 2;
        const float4 w1v = *(const float4*)&w1[c4];
        #pragma unroll
        for (int p = 0; p < 4; ++p) {
            const int r = w + (p << 3);                  // 0..31
            const float4 xv = *(const float4*)&x[(b0 + r) * C_NODES + c4];
            float4 o;
            o.x = xv.x * w1v.x; o.y = xv.y * w1v.y;
            o.z = xv.z * w1v.z; o.w = xv.w * w1v.w;
            *(float4*)&o1t[(r << 8) + c4] = o;
        }
    }
    __syncthreads();

    const float c0 = w2[0], c1 = w2[1], c2 = w2[2], c3 = w2[3];
    const int l4 = lane << 2;

    float2 acc[BT];
    #pragma unroll
    for (int b = 0; b < BT; ++b) { acc[b].x = 0.f; acc[b].y = 0.f; }

    // ---- main loop: zero address math; static offsets -> compiler pipelines
    #pragma unroll
    for (int b = 0; b < BT; ++b) {
        const float4 ov = *(const float4*)&o1t[(b << 8) + l4];   // linear row read
        const float2 oi = *(const float2*)&o1t[(b << 8) + i0];   // uniform bcast
        #pragma unroll
        for (int k = 0; k < 4; ++k) {
            const float oj = ((const float*)&ov)[k];
            {   const float d = oi.x - oj, a = fabsf(d);
                const float t3 = __builtin_fmaf(a, __builtin_fmaf(a,
                                   __builtin_fmaf(a, c3, c2), c1), c0);
                acc[b].x = __builtin_fmaf(d * fmaxf(t3, 0.01f * t3),
                                          ((const float*)&wv0)[k], acc[b].x); }
            {   const float d = oi.y - oj, a = fabsf(d);
                const float t3 = __builtin_fmaf(a, __builtin_fmaf(a,
                                   __builtin_fmaf(a, c3, c2), c1), c0);
                acc[b].y = __builtin_fmaf(d * fmaxf(t3, 0.01f * t3),
                                          ((const float*)&wv1)[k], acc[b].y); }
        }
    }

    // ---- epilogue: per-wave transpose-reduce in reused o1t (wave-private region)
    __syncthreads();                       // all main-loop reads of o1t done
    float* red = &o1t[w * 1088];           // 16 rows x 68 words per wave
    #pragma unroll
    for (int r = 0; r < 4; ++r) {
        #pragma unroll
        for (int bb = 0; bb < 8; ++bb) {
            red[(bb * 2 + 0) * 68 + lane] = acc[r * 8 + bb].x;
            red[(bb * 2 + 1) * 68 + lane] = acc[r * 8 + bb].y;
        }
        float s = 0.f;
        const int base = (lane & 15) * 68 + ((lane >> 4) << 4);
        #pragma unroll
        for (int c = 0; c < 4; ++c) {
            const float4 v = *(const float4*)&red[base + (c << 2)];
            s += (v.x + v.y) + (v.z + v.w);
        }
        s += __shfl_xor(s, 16, 64);
        s += __shfl_xor(s, 32, 64);
        if (lane < 16)
            out[(b0 + r * 8 + (lane >> 1)) * C_NODES + i0 + (lane & 1)] = s;
    }
}

extern "C" void kernel_launch(void* const* d_in, const int* in_sizes, int n_in,
                              void* d_out, int out_size, void* d_ws, size_t ws_size,
                              hipStream_t stream) {
    const float* x  = (const float*)d_in[0];
    const float* w1 = (const float*)d_in[1];
    const float* w2 = (const float*)d_in[2];
    const float* w3 = (const float*)d_in[3];
    float* out = (float*)d_out;

    const int B = in_sizes[0] / C_NODES;          // 1024
    dim3 grid(B / BT, C_NODES / NPB);             // 32 x 16 = 512 blocks = 2/CU
    son_kernel<<<grid, 512, 0, stream>>>(x, w1, w2, w3, out);
}

// Round 10
// 21.745 us; speedup vs baseline: 1.2349x; 1.0954x over previous
//
#include <hip/hip_runtime.h>

// Son_swapnet: out[b,i] = sum_j d*leaky01(t3)*(-w3[e(i,j)]),
//   d  = o1[b][i] - o1[b][j],  o1 = x*w1
//   t3 = c0 + a*(c1 + a*(c2 + a*c3)), a = |d| (abs folds into fma src-modifier)
//   leaky01(t) = max(t, 0.01t);  j==i term is exactly 0 (wrow entry = 0).
//
// Geometry: 512 thr = 8 waves; wave owns TWO nodes (i0, i0+1) -> one ov read
// feeds 8 evals (RPW=2 halves the dominant LDS stream vs R4). BT=32 batches;
// half-wave j-split (lanes 0-31: j in [0,128), lanes 32-63: j in [128,256)),
// merged by one shfl_xor. 16 nodes/block -> grid 32x16=512 blocks = 2/CU,
// 16 waves/CU (the measured-best regime). LDS 48KB. No build_W prepass.

#define C_NODES 256
#define BT      32     // batches per block (lane&31)
#define NW      8      // waves per block
#define NPB     16     // nodes per block (2 per wave)

__global__ __launch_bounds__(512, 4) void son_kernel(
    const float* __restrict__ x, const float* __restrict__ w1,
    const float* __restrict__ w2, const float* __restrict__ w3,
    float* __restrict__ out)
{
    // o1t: [row 0..31][channel], 256 words/row, 16B-chunk XOR-swizzled by (row&7)
    __shared__ __align__(16) float o1t[BT * C_NODES];       // 32 KiB
    __shared__ __align__(16) float wrow[NPB * C_NODES];     // 16 KiB: [r][j] = -w3[e]

    const int t  = threadIdx.x;
    const int b0 = blockIdx.x * BT;

    // ---- stage o1t (coalesced global float4 reads; swizzled LDS writes)
    {
        const int chunk = t & 63;
        const int c4    = chunk << 2;
        const float4 w1v = *(const float4*)&w1[c4];
        #pragma unroll
        for (int p = 0; p < 4; ++p) {
            const int row = (t >> 6) + (p << 3);          // 0..31
            const float4 xv = *(const float4*)&x[(b0 + row) * C_NODES + c4];
            float4 o;
            o.x = xv.x * w1v.x; o.y = xv.y * w1v.y;
            o.z = xv.z * w1v.z; o.w = xv.w * w1v.w;
            const int phys = chunk ^ (row & 7);
            *(float4*)&o1t[(row << 8) + (phys << 2)] = o;
        }
    }

    // ---- gather wrow[r][j] = -w3[e(i_r,j)]  (2 node-rows per wave, L2-resident)
    {
        const int lane = t & 63;
        const int wv_  = t >> 6;
        #pragma unroll
        for (int rr = 0; rr < 2; ++rr) {
            const int r = wv_ * 2 + rr;
            const int i = blockIdx.y * NPB + r;
            float4 wv;
            #pragma unroll
            for (int k = 0; k < 4; ++k) {
                const int j = 4 * lane + k;
                const int p = (i < j) ? i : j, q = (i < j) ? j : i;
                ((float*)&wv)[k] = (i == j) ? 0.f
                                 : -w3[(p * (511 - p)) / 2 + q - p - 1];
            }
            *(float4*)&wrow[(r << 8) + (lane << 2)] = wv;
        }
    }
    __syncthreads();

    const int lane    = t & 63;
    const int w       = __builtin_amdgcn_readfirstlane(t >> 6);
    const int r0      = 2 * w;                       // node slot pair
    const int i0      = blockIdx.y * NPB + r0;
    const int row     = lane & 31;
    const int hbit    = lane & 32;                   // j-half selector
    const int swz     = row & 7;
    const int rowbase = row << 8;

    const float c0 = w2[0], c1 = w2[1], c2 = w2[2], c3 = w2[3];

    // own-node o1 values (swizzled one-time reads)
    const float oi0 = o1t[rowbase + ((((i0 >> 2) ^ swz) << 2) | (i0 & 3))];
    const float oi1 = o1t[rowbase + (((((i0 + 1) >> 2) ^ swz) << 2) | ((i0 + 1) & 3))];

    float acc0 = 0.f, acc1 = 0.f;

    #pragma unroll 4
    for (int jc = 0; jc < 32; ++jc) {
        const int cj = hbit + jc;                               // chunk 0..63
        const float4 ov = *(const float4*)&o1t[rowbase + ((cj ^ swz) << 2)];
        const float4 wa = *(const float4*)&wrow[(r0 << 8) + (cj << 2)];
        const float4 wb = *(const float4*)&wrow[((r0 + 1) << 8) + (cj << 2)];
        #pragma unroll
        for (int k = 0; k < 4; ++k) {
            const float oj = ((const float*)&ov)[k];
            {   const float d = oi0 - oj, a = fabsf(d);
                const float t3 = __builtin_fmaf(a, __builtin_fmaf(a,
                                   __builtin_fmaf(a, c3, c2), c1), c0);
                acc0 = __builtin_fmaf(d * fmaxf(t3, 0.01f * t3),
                                      ((const float*)&wa)[k], acc0); }
            {   const float d = oi1 - oj, a = fabsf(d);
                const float t3 = __builtin_fmaf(a, __builtin_fmaf(a,
                                   __builtin_fmaf(a, c3, c2), c1), c0);
                acc1 = __builtin_fmaf(d * fmaxf(t3, 0.01f * t3),
                                      ((const float*)&wb)[k], acc1); }
        }
    }

    // merge j-halves: after xor every lane holds the full sums
    acc0 += __shfl_xor(acc0, 32, 64);
    acc1 += __shfl_xor(acc1, 32, 64);

    // lanes 0-31 store node i0, lanes 32-63 store node i0+1 (same batch rows)
    const int node = i0 + (hbit >> 5);
    const float v  = hbit ? acc1 : acc0;
    out[(b0 + row) * C_NODES + node] = v;
}

extern "C" void kernel_launch(void* const* d_in, const int* in_sizes, int n_in,
                              void* d_out, int out_size, void* d_ws, size_t ws_size,
                              hipStream_t stream) {
    const float* x  = (const float*)d_in[0];
    const float* w1 = (const float*)d_in[1];
    const float* w2 = (const float*)d_in[2];
    const float* w3 = (const float*)d_in[3];
    float* out = (float*)d_out;

    const int B = in_sizes[0] / C_NODES;          // 1024
    dim3 grid(B / BT, C_NODES / NPB);             // 32 x 16 = 512 blocks = 2/CU
    son_kernel<<<grid, 512, 0, stream>>>(x, w1, w2, w3, out);
}

// Round 12
// 21.487 us; speedup vs baseline: 1.2498x; 1.0120x over previous
//
#include <hip/hip_runtime.h>

// Son_swapnet: out[b,i] = sum_j d*leaky01(t3)*(-w3[e(i,j)]),
//   d = o1[b][i]-o1[b][j], o1 = x*w1
//   s = d*d; t3 = (c0+c2*s) + |d|*(c1+c3*s);  leaky01(t) = max(t, 0.01t)
// j==i term is exactly 0 (wpair entry = 0).
//
// R10 geometry (512 thr = 8 waves, 2 nodes/wave, BT=32, half-wave j-split,
// 512 blocks = 2/CU) + PACKED fp32 math (v_pk_fma/mul/max via f32x2):
// 10 packed instr / 2 evals. W stored node-INTERLEAVED in LDS so each packed
// FMA's W operand is an adjacent register pair straight out of ds_read_b128.
// R11 compile fix: hand-unrolled k-body (shufflevector needs literal indices).

#define C_NODES 256
#define BT      32
#define NW      8
#define NPB     16     // nodes per block (2 per wave)

typedef float f32x2 __attribute__((ext_vector_type(2)));
typedef float f32x4 __attribute__((ext_vector_type(4)));

__global__ __launch_bounds__(512, 4) void son_kernel(
    const float* __restrict__ x, const float* __restrict__ w1,
    const float* __restrict__ w2, const float* __restrict__ w3,
    float* __restrict__ out)
{
    // o1t: [row 0..31][channel], 16B-chunk XOR-swizzled by (row&7)
    __shared__ __align__(16) float o1t[BT * C_NODES];        // 32 KiB
    // wpair[w][j][2]: interleaved (-w3[e(i0,j)], -w3[e(i1,j)]) per wave
    __shared__ __align__(16) float wpair[NW * C_NODES * 2];  // 16 KiB

    const int t  = threadIdx.x;
    const int b0 = blockIdx.x * BT;

    // ---- stage o1t (coalesced float4 reads; swizzled LDS writes)
    {
        const int chunk = t & 63;
        const int c4    = chunk << 2;
        const float4 w1v = *(const float4*)&w1[c4];
        #pragma unroll
        for (int p = 0; p < 4; ++p) {
            const int row = (t >> 6) + (p << 3);          // 0..31
            const float4 xv = *(const float4*)&x[(b0 + row) * C_NODES + c4];
            float4 o;
            o.x = xv.x * w1v.x; o.y = xv.y * w1v.y;
            o.z = xv.z * w1v.z; o.w = xv.w * w1v.w;
            const int phys = chunk ^ (row & 7);
            *(float4*)&o1t[(row << 8) + (phys << 2)] = o;
        }
    }

    // ---- gather wpair[w][j] = (-w3[e(i0,j)], -w3[e(i1,j)])  (L2-resident, once)
    {
        const int lane = t & 63;
        const int wv_  = t >> 6;
        const int i0g  = blockIdx.y * NPB + 2 * wv_;
        #pragma unroll
        for (int p = 0; p < 2; ++p) {
            const int j0 = (p * 64 + lane) * 2;           // 2 j per float4
            float4 v;
            #pragma unroll
            for (int jj = 0; jj < 2; ++jj) {
                const int j = j0 + jj;
                #pragma unroll
                for (int n = 0; n < 2; ++n) {
                    const int i = i0g + n;
                    const int pp = (i < j) ? i : j, qq = (i < j) ? j : i;
                    ((float*)&v)[jj * 2 + n] = (i == j) ? 0.f
                        : -w3[(pp * (511 - pp)) / 2 + qq - pp - 1];
                }
            }
            *(float4*)&wpair[(wv_ << 9) + (j0 << 1)] = v;
        }
    }
    __syncthreads();

    const int lane    = t & 63;
    const int w       = __builtin_amdgcn_readfirstlane(t >> 6);
    const int i0      = blockIdx.y * NPB + 2 * w;
    const int row     = lane & 31;
    const int hbit    = lane & 32;                 // j-half selector
    const int swz     = row & 7;
    const int rowbase = row << 8;

    const float c0 = w2[0], c1 = w2[1], c2 = w2[2], c3 = w2[3];
    const f32x2 c0v = {c0, c0}, c1v = {c1, c1}, c2v = {c2, c2}, c3v = {c3, c3};

    // own-node o1 pair (swizzled one-time reads)
    const float oi0 = o1t[rowbase + ((((i0 >> 2) ^ swz) << 2) | (i0 & 3))];
    const float oi1 = o1t[rowbase + (((((i0 + 1) >> 2) ^ swz) << 2) | ((i0 + 1) & 3))];
    const f32x2 oi2 = {oi0, oi1};

    f32x2 acc = {0.f, 0.f};
    const float* wbase = &wpair[w << 9];

    // one packed edge-pair evaluation; OJ = scalar float, WPK = f32x2
    #define EDGE_PK(OJ, WPK)                                              \
        {                                                                 \
            const f32x2 ojv = {(OJ), (OJ)};                               \
            const f32x2 d   = oi2 - ojv;                                  \
            const f32x2 s   = d * d;                                      \
            const f32x2 pe  = __builtin_elementwise_fma(s, c2v, c0v);     \
            const f32x2 po  = __builtin_elementwise_fma(s, c3v, c1v);     \
            const f32x2 a   = __builtin_elementwise_max(d, -d);           \
            const f32x2 t3  = __builtin_elementwise_fma(a, po, pe);       \
            const f32x2 t3s = __builtin_elementwise_max(t3, 0.01f * t3);  \
            const f32x2 u   = d * t3s;                                    \
            acc = __builtin_elementwise_fma(u, (WPK), acc);               \
        }

    #pragma unroll 4
    for (int jc = 0; jc < 32; ++jc) {
        const int cj = hbit + jc;                               // chunk 0..63
        const f32x4 ov  = *(const f32x4*)&o1t[rowbase + ((cj ^ swz) << 2)];
        const f32x4 wv0 = *(const f32x4*)&wbase[(cj << 3) + 0];  // j=4cj,4cj+1
        const f32x4 wv1 = *(const f32x4*)&wbase[(cj << 3) + 4];  // j=4cj+2,4cj+3
        EDGE_PK(ov.x, __builtin_shufflevector(wv0, wv0, 0, 1));
        EDGE_PK(ov.y, __builtin_shufflevector(wv0, wv0, 2, 3));
        EDGE_PK(ov.z, __builtin_shufflevector(wv1, wv1, 0, 1));
        EDGE_PK(ov.w, __builtin_shufflevector(wv1, wv1, 2, 3));
    }
    #undef EDGE_PK

    // merge j-halves (lane l <-> l+32): every lane then holds full sums
    float a0 = acc.x, a1 = acc.y;
    a0 += __shfl_xor(a0, 32, 64);
    a1 += __shfl_xor(a1, 32, 64);

    // lanes 0-31 store node i0, lanes 32-63 store node i0+1
    const int node = i0 + (hbit >> 5);
    out[(b0 + row) * C_NODES + node] = hbit ? a1 : a0;
}

extern "C" void kernel_launch(void* const* d_in, const int* in_sizes, int n_in,
                              void* d_out, int out_size, void* d_ws, size_t ws_size,
                              hipStream_t stream) {
    const float* x  = (const float*)d_in[0];
    const float* w1 = (const float*)d_in[1];
    const float* w2 = (const float*)d_in[2];
    const float* w3 = (const float*)d_in[3];
    float* out = (float*)d_out;

    const int B = in_sizes[0] / C_NODES;          // 1024
    dim3 grid(B / BT, C_NODES / NPB);             // 32 x 16 = 512 blocks = 2/CU
    son_kernel<<<grid, 512, 0, stream>>>(x, w1, w2, w3, out);
}